// Round 12
// baseline (506.807 us; speedup 1.0000x reference)
//
#include <hip/hip_runtime.h>
#include <math.h>

#ifndef M_PI
#define M_PI 3.14159265358979323846
#endif

// B=64, C=3, H=W=512.
// Loss = mean_b | mean_hf(log10 PSD(gen_b)) - mean_hf(log10 PSD(tgt_b)) |
// hf region: element EXCLUDED iff ky and kx both in [0,64)u[448,512).
// With ky = cc + 8dd + 64e: ky<64 <=> e==0, ky>=448 <=> e==7. count = 245760.
//
// FFT: 512 = 8*8*8 Cooley-Tukey, per-wave, 8 complex regs/lane, wave-private
// LDS transposes, compile-time-only ordering (R6, verified absmax 0.0).
// R7 (verified): col = one wave per conjugate pair, zero barriers, no atomics.
// R8 (REGRESSED): 16-row blocks -> occupancy 40%. Reverted.
// R9 (verified): writer-contiguous scratch; row 167->147us.
// R10 (NEUTRAL): float4 loads; VGPR stayed 32 (compiler re-serialized) ->
//   load-depth not the limiter. All pipes <30% busy; implied wave latency
//   ~130K cy >> ~3.5K serial model => CORRELATED PHASE STALLS.
//
// R11 (resubmitted verbatim -- 3x acquisition timeout, never ran):
//   phase decorrelation.
//   Row: 4-wave/256-thr blocks (4 rows), 16KB LDS -> 8 independent blocks/CU,
//   32 waves = 100% occupancy; some block is always in its load phase.
//   Scratch layout [img][rg4][col][j4] (rg4=r>>2, j4=r&3), flat float2 idx
//     img*2^18 + rg4*2048 + col*4 + j4.  Writer still fully streaming
//   (16KB contiguous per block, 512B per wave-inst). Col read granule drops
//   64B->32B; mitigated by bijective XCD swizzle (m204): all blocks of an
//   image on one XCD -> its L2 dedupes the 64B lines shared by col pairs.
//   Input loads reverted to R9 scalar (R10's pack only added conflicts).
//
// ws layout: [0,2048) tw[256] ; [2048,3072) double accum[128] ;
//            [4096, 4096+262144) double2 partial[64*256] ;
//            [266240, ...) scratch (16 KB-aligned).
// col index encodes kx: col(kx) = 64*(kx>>6) + 8*(kx&7) + ((kx>>3)&7)

__device__ __forceinline__ float2 cmulf(float2 a, float2 b) {
    return make_float2(fmaf(a.x, b.x, -(a.y * b.y)), fmaf(a.x, b.y, a.y * b.x));
}
__device__ __forceinline__ float2 caddf(float2 a, float2 b){ return make_float2(a.x+b.x, a.y+b.y); }
__device__ __forceinline__ float2 csubf(float2 a, float2 b){ return make_float2(a.x-b.x, a.y-b.y); }

// Bijective XCD-chunk swizzle (nwg % 8 == 0): physical block b -> work id.
__device__ __forceinline__ int xcd_swizzle(int b, int nwg) {
    return (b & 7) * (nwg >> 3) + (b >> 3);
}

// Wave-local LDS ordering point: compile-time only (DS pipe is in-order per wave).
__device__ __forceinline__ void lds_order() {
    __builtin_amdgcn_sched_barrier(0);
}

// natural-order 8-point DFT: v[k] <- sum_a v[a] W_8^{ak}
__device__ __forceinline__ void dft8(float2 v[8]) {
    const float S = 0.70710678118654752440f;
    float2 a0=caddf(v[0],v[4]), a1=caddf(v[1],v[5]), a2=caddf(v[2],v[6]), a3=caddf(v[3],v[7]);
    float2 b0=csubf(v[0],v[4]);
    float2 t1=csubf(v[1],v[5]);
    float2 t2=csubf(v[2],v[6]);
    float2 t3=csubf(v[3],v[7]);
    float2 b1=make_float2(S*(t1.x+t1.y), S*(t1.y-t1.x));   // *(S,-S) = W8^1
    float2 b2=make_float2(t2.y, -t2.x);                    // *(-i)   = W8^2
    float2 b3=make_float2(S*(t3.y-t3.x), -S*(t3.x+t3.y));  // *(-S,-S)= W8^3
    float2 c0=caddf(a0,a2), c1=caddf(a1,a3), c2=csubf(a0,a2);
    float2 u3=csubf(a1,a3); float2 c3=make_float2(u3.y,-u3.x);
    float2 d0=caddf(b0,b2), d1=caddf(b1,b3), d2=csubf(b0,b2);
    float2 w3=csubf(b1,b3); float2 d3=make_float2(w3.y,-w3.x);
    v[0]=caddf(c0,c1); v[4]=csubf(c0,c1);
    v[2]=caddf(c2,c3); v[6]=csubf(c2,c3);
    v[1]=caddf(d0,d1); v[5]=csubf(d0,d1);
    v[3]=caddf(d2,d3); v[7]=csubf(d2,d3);
}

// v[c] *= w^c, c=1..7. Power tree: short dependency chain, good ILP.
__device__ __forceinline__ void twapply(float2 v[8], float2 w) {
    const float2 w2 = cmulf(w,  w);
    const float2 w3 = cmulf(w2, w);
    const float2 w4 = cmulf(w2, w2);
    const float2 w5 = cmulf(w2, w3);
    const float2 w6 = cmulf(w3, w3);
    const float2 w7 = cmulf(w4, w3);
    v[1] = cmulf(v[1], w);
    v[2] = cmulf(v[2], w2);
    v[3] = cmulf(v[3], w3);
    v[4] = cmulf(v[4], w4);
    v[5] = cmulf(v[5], w5);
    v[6] = cmulf(v[6], w6);
    v[7] = cmulf(v[7], w7);
}

// Per-wave 512-pt FFT. In: v[a] = x[64a + lane]. Out: lane L, reg e = X[(L>>3) + 8*(L&7) + 64e].
// W = this wave's PRIVATE 512-float2 LDS region. No block-wide sync inside.
__device__ __forceinline__ void fft512_reg(float2 v[8], float2* __restrict__ W,
                                           const float2* __restrict__ twg, int lane) {
    dft8(v);
    twapply(v, twg[lane]);                                   // W_512^m, m = lane
    // T1 write: slot(c,m) = 64c + ((m + 2c)&63)  -> rotation: bijective, bank floor
#pragma unroll
    for (int c = 0; c < 8; ++c) W[(c<<6) + ((lane + 2*c)&63)] = v[c];
    lds_order();
    {   // T1 read: lane (c,p) takes m = 8b+p
        const int c = lane>>3, p = lane&7, base = c<<6, off = p + 2*c;
#pragma unroll
        for (int bb = 0; bb < 8; ++bb) v[bb] = W[base + (((bb<<3) + off)&63)];
    }
    lds_order();
    dft8(v);
    twapply(v, twg[(lane&7)<<3]);                            // W_64^p = W_512^{8p}
    {   // T2 write: slot(c,p,d) at 64c + ((8d + (p^d) + 2c)&63)  (XOR: bijective)
        const int c = lane>>3, p = lane&7, base = c<<6, r2 = 2*c;
#pragma unroll
        for (int d = 0; d < 8; ++d) W[base + (((d<<3) + (p^d) + r2)&63)] = v[d];
    }
    lds_order();
    {   // T2 read: lane (c,d) takes p = 0..7
        const int c = lane>>3, d = lane&7, base = c<<6, off = (d<<3) + 2*c;
#pragma unroll
        for (int p = 0; p < 8; ++p) v[p] = W[base + ((off + (p^d))&63)];
    }
    lds_order();
    dft8(v);
}

__global__ void twiddle_kernel(float2* __restrict__ tw) {
    const int k = threadIdx.x;            // 0..255
    const double ang = -2.0 * M_PI * (double)k / 512.0;
    tw[k] = make_float2((float)cos(ang), (float)sin(ang));
}

// Pass 1 (R11): 256 thr = 4 waves = 4 rows. Grid = chunk*128, XCD-swizzled.
// Per wave: scalar loads + gray + row FFT; block gathers to streaming scratch.
__global__ __launch_bounds__(256, 8)
void row_fft_kernel(const float* __restrict__ gen, const float* __restrict__ tgt,
                    const float2* __restrict__ twg, float2* __restrict__ scratch,
                    int b0, int nwg) {
    __shared__ float2 SBUF[4 * 512];      // 16 KB: per-wave FFT region, then out-staging
    const int w = xcd_swizzle((int)blockIdx.x, nwg);
    const int tid = threadIdx.x, wave = tid>>6, lane = tid&63;
    const int img = w>>7, rg4 = w&127;
    const int b = b0 + img, r = (rg4<<2) + wave;

    const size_t rowoff = ((size_t)b * 3 * 512 + r) * 512;
    const float* gR = gen + rowoff; const float* gG = gR + 262144; const float* gB = gG + 262144;
    const float* tR = tgt + rowoff; const float* tG = tR + 262144; const float* tB = tG + 262144;

    float2 v[8];
#pragma unroll
    for (int a = 0; a < 8; ++a) {          // coalesced dword loads, 64 lanes consecutive
        const int idx = (a<<6) + lane;
        const float gg = fmaf(0.299f, gR[idx], fmaf(0.587f, gG[idx], fmaf(0.114f, gB[idx], 1.0f))) * 0.5f;
        const float tt = fmaf(0.299f, tR[idx], fmaf(0.587f, tG[idx], fmaf(0.114f, tB[idx], 1.0f))) * 0.5f;
        v[a] = make_float2(gg, tt);        // (gray01(gen), gray01(tgt))
    }

    float2* W = SBUF + (wave<<9);
    fft512_reg(v, W, twg, lane);

    // out-staging (overlays own FFT region; same-wave WAR safe via in-order DS pipe):
    // region = wave (row r), slot = (col + 8*wave)&511, col = 64e + lane
#pragma unroll
    for (int e = 0; e < 8; ++e) {
        const int col = (e<<6) + lane;
        W[(col + (wave<<3)) & 511] = v[e];
    }
    __syncthreads();                       // REAL barrier: gather reads all 4 regions

    // gather + store: scratch[img][rg4][col][j4], flat = obase + col*4 + j4.
    // thread (cg=tid>>2, j4=tid&3): out idx = it*256 + tid -> block writes one
    // contiguous 16KB region; 512B per wave-inst. LDS: region j4, elem
    // (col + 8*j4)&511 -> 4 lanes/bank-pair = floor.
    const size_t obase = ((size_t)img << 18) + ((size_t)rg4 << 11);
    const int cg = tid>>2, j4 = tid&3;
    float2* sj = SBUF + (j4<<9);
#pragma unroll
    for (int it = 0; it < 8; ++it) {
        const int col = cg + (it<<6);
        scratch[obase + (it<<8) + tid] = sj[(col + (j4<<3)) & 511];
    }
}

// PSD combine for one element: F1 = Z[ky][kx], F2 = Z[-ky][-kx].
__device__ __forceinline__ void accum_psd(float2 F1, float2 F2, double& sg, double& st) {
    const float ar = 0.5f*(F1.x + F2.x), ai = 0.5f*(F1.y - F2.y);   // gen spectrum
    const float br = 0.5f*(F1.y + F2.y), bi = 0.5f*(F2.x - F1.x);   // tgt spectrum
    const float pg = fmaf(ar, ar, ai*ai) + 1e-10f;
    const float pt = fmaf(br, br, bi*bi) + 1e-10f;
    sg += (double)log10f(pg);
    st += (double)log10f(pt);
}

// Pass 2 (R7 + R11 layout): one WAVE per conjugate column pair. Block = 256 thr.
// Grid = chunk*64, XCD-swizzled (same img->XCD map as row). NO __syncthreads.
__global__ __launch_bounds__(256, 4)
void col_fft_reduce_kernel(const float2* __restrict__ scratch,
                           const float2* __restrict__ twg,
                           double2* __restrict__ partial, int b0, int nwg) {
    __shared__ float2 SBUF[4 * 512];      // 16 KB: one private 512-float2 region per wave
    const int w = xcd_swizzle((int)blockIdx.x, nwg);
    const int tid = threadIdx.x, wave = tid>>6, lane = tid&63;
    const int gw = (w<<2) + wave;              // global wave (work) id in dispatch
    const int img = gw>>8, t = gw&255;
    const int b = b0 + img;
    const int kxA = t;
    const int kxB = (t == 0) ? 256 : 512 - t;
    const int colA = ((kxA>>6)<<6) + ((kxA&7)<<3) + ((kxA>>3)&7);
    const int colB = ((kxB>>6)<<6) + ((kxB&7)<<3) + ((kxB>>3)&7);
    float2* W = SBUF + (wave<<9);

    // r = 64a + lane -> rg4 = 16a + (lane>>2), j4 = lane&3:
    // idx = img*2^18 + rg4*2048 + col*4 + j4 = base + a*32768
    const size_t lanoff = ((size_t)(lane>>2)<<11) + (lane&3);
    const float2* srcA = scratch + ((size_t)img<<18) + ((size_t)colA<<2) + lanoff;
    const float2* srcB = scratch + ((size_t)img<<18) + ((size_t)colB<<2) + lanoff;
    float2 va[8], vb[8];
#pragma unroll
    for (int a = 0; a < 8; ++a) va[a] = srcA[a<<15];
#pragma unroll
    for (int a = 0; a < 8; ++a) vb[a] = srcB[a<<15];            // prefetch under FFT A

    fft512_reg(va, W, twg, lane);

    const int cc = lane>>3, dd = lane&7;
    const int kyb = cc + (dd<<3);            // ky = kyb + 64e

    // publish A natural-ky, read reversed into regs (wave-private, in-order DS)
#pragma unroll
    for (int e = 0; e < 8; ++e) W[kyb + (e<<6)] = va[e];
    lds_order();
    float2 aRev[8];
#pragma unroll
    for (int e = 0; e < 8; ++e) aRev[e] = W[(512 - (kyb + (e<<6))) & 511];
    lds_order();                             // keep FFT B's writes after these reads

    fft512_reg(vb, W, twg, lane);

#pragma unroll
    for (int e = 0; e < 8; ++e) W[kyb + (e<<6)] = vb[e];
    lds_order();
    float2 bRev[8];
#pragma unroll
    for (int e = 0; e < 8; ++e) bRev[e] = W[(512 - (kyb + (e<<6))) & 511];
    lds_order();

    // exclusion: column in box-kx  =>  skip e==0 (ky<64) and e==7 (ky>=448)
    const bool kxinA = (t < 64);             // kxA in [0,64)
    const bool kxinB = (t >= 1 && t <= 64);  // kxB = 512-t in [448,512)

    double sg = 0.0, st = 0.0;
    if (t == 0) {   // both columns self-conjugate: partner is own reversed
#pragma unroll
        for (int e = 0; e < 8; ++e) {
            if (!(kxinA && (e == 0 || e == 7))) accum_psd(va[e], aRev[e], sg, st);
            accum_psd(vb[e], bRev[e], sg, st);   // kx=256 never in box
        }
    } else {        // partner of A is B and vice versa
#pragma unroll
        for (int e = 0; e < 8; ++e) {
            if (!(kxinA && (e == 0 || e == 7))) accum_psd(va[e], bRev[e], sg, st);
            if (!(kxinB && (e == 0 || e == 7))) accum_psd(vb[e], aRev[e], sg, st);
        }
    }
#pragma unroll
    for (int off = 32; off; off >>= 1) {
        sg += __shfl_down(sg, off);
        st += __shfl_down(st, off);
    }
    if (lane == 0) partial[((size_t)b<<8) + t] = make_double2(sg, st);
}

// Sum the 256 per-pair partials of each image into accum[128]. Grid = 64 blocks.
__global__ __launch_bounds__(256)
void reduce_partial_kernel(const double2* __restrict__ partial,
                           double* __restrict__ accum) {
    __shared__ double2 red[4];
    const int img = blockIdx.x, tid = threadIdx.x, wave = tid>>6, lane = tid&63;
    const double2 p = partial[((size_t)img<<8) + tid];
    double sg = p.x, st = p.y;
#pragma unroll
    for (int off = 32; off; off >>= 1) {
        sg += __shfl_down(sg, off);
        st += __shfl_down(st, off);
    }
    if (lane == 0) red[wave] = make_double2(sg, st);
    __syncthreads();
    if (tid == 0) {
        double SG = 0.0, ST = 0.0;
#pragma unroll
        for (int w = 0; w < 4; ++w) { SG += red[w].x; ST += red[w].y; }
        accum[img] = SG;
        accum[64 + img] = ST;
    }
}

__global__ void finalize_kernel(const double* __restrict__ accum,
                                float* __restrict__ out) {
    const int lane = threadIdx.x;   // 64
    double d = fabs(accum[lane] - accum[64 + lane]) * (1.0 / 245760.0);
#pragma unroll
    for (int off = 32; off; off >>= 1) d += __shfl_down(d, off);
    if (lane == 0) out[0] = (float)(d * (1.0 / 64.0));   // WEIGHT = 1.0
}

extern "C" void kernel_launch(void* const* d_in, const int* in_sizes, int n_in,
                              void* d_out, int out_size, void* d_ws, size_t ws_size,
                              hipStream_t stream) {
    (void)in_sizes; (void)n_in; (void)out_size;
    const float* gen = (const float*)d_in[0];
    const float* tgt = (const float*)d_in[1];
    float*   out     = (float*)d_out;
    float2*  tw      = (float2*)d_ws;
    double*  accum   = (double*)((char*)d_ws + 2048);
    double2* partial = (double2*)((char*)d_ws + 4096);            // 64*256*16 B = 256 KB
    float2*  scratch = (float2*)((char*)d_ws + 266240);           // 65*4096

    const size_t per_img = (size_t)512 * 512 * sizeof(float2);
    const size_t avail = (ws_size > 266240) ? (ws_size - 266240) : 0;
    int chunk = 64;                      // shrinks to fit ws (observed: 32 -> 64 MiB)
    while (chunk > 1 && (size_t)chunk * per_img > avail) chunk >>= 1;

    twiddle_kernel<<<1, 256, 0, stream>>>(tw);
    for (int b0 = 0; b0 < 64; b0 += chunk) {
        const int nwr = chunk * 128;     // %8==0 for chunk>=1
        const int nwc = chunk * 64;
        row_fft_kernel<<<dim3(nwr), dim3(256), 0, stream>>>(gen, tgt, tw, scratch, b0, nwr);
        col_fft_reduce_kernel<<<dim3(nwc), dim3(256), 0, stream>>>(scratch, tw, partial, b0, nwc);
    }
    reduce_partial_kernel<<<dim3(64), dim3(256), 0, stream>>>(partial, accum);
    finalize_kernel<<<1, 64, 0, stream>>>(accum, out);
}

// Round 13
// 499.614 us; speedup vs baseline: 1.0144x; 1.0144x over previous
//
#include <hip/hip_runtime.h>
#include <math.h>

#ifndef M_PI
#define M_PI 3.14159265358979323846
#endif

// B=64, C=3, H=W=512.
// Loss = mean_b | mean_hf(log10 PSD(gen_b)) - mean_hf(log10 PSD(tgt_b)) |
// hf region: element EXCLUDED iff ky and kx both in [0,64)u[448,512).
// With ky = cc + 8dd + 64e: ky<64 <=> e==0, ky>=448 <=> e==7. count = 245760.
//
// FFT: 512 = 8*8*8 Cooley-Tukey, per-wave, 8 complex regs/lane, wave-private
// LDS transposes, compile-time-only ordering (R6, verified absmax 0.0).
// R7 (verified): col = one wave per conjugate pair, zero barriers, no atomics.
// R8 (REGRESSED): 16-row blocks -> occupancy 40%. Reverted.
// R9 (verified): writer-contiguous scratch; row 167->147us.
// R10 (NEUTRAL): float4 loads; VGPR stayed 32 -> compiler re-serialized the
//   loads; depth never changed. Pack mapping itself verified (absmax 0.0).
// R11 (NEUTRAL): 4-wave blocks / phase decorrelation: row unchanged 147us,
//   occ 76%. Theory dead. VGPR=32 in EVERY variant.
//
// R12 (this round): FORCE load depth.
//   Little's law: 6.3TB/s needs ~22KB in flight/CU; at 24 waves/CU that is
//   ~4 dword loads outstanding/wave. VGPR=32 cannot hold them -> observed
//   2.3TB/s (36%). Fix: 12 float4 loads into named regs + sched_barrier(0)
//   pinning all loads before any consumer (48 VGPR payload forced live) +
//   __launch_bounds__(256,4) raising the VGPR cap to 128. Col gets the same
//   treatment (16 loads pinned; vb rides through FFT A as real prefetch).
//   Redistribute via R10's verified LDS pack. KEY DIAGNOSTIC: VGPR_Count
//   must jump to ~64-96; if it stays 32 the compiler won again.
//
// ws layout: [0,2048) tw[256] ; [2048,3072) double accum[128] ;
//            [4096, 4096+262144) double2 partial[64*256] ;
//            [266240, ...) scratch (16 KB-aligned).
// col index encodes kx: col(kx) = 64*(kx>>6) + 8*(kx&7) + ((kx>>3)&7)

__device__ __forceinline__ float2 cmulf(float2 a, float2 b) {
    return make_float2(fmaf(a.x, b.x, -(a.y * b.y)), fmaf(a.x, b.y, a.y * b.x));
}
__device__ __forceinline__ float2 caddf(float2 a, float2 b){ return make_float2(a.x+b.x, a.y+b.y); }
__device__ __forceinline__ float2 csubf(float2 a, float2 b){ return make_float2(a.x-b.x, a.y-b.y); }

__device__ __forceinline__ float gray01(float R, float G, float B) {
    return fmaf(0.299f, R, fmaf(0.587f, G, fmaf(0.114f, B, 1.0f))) * 0.5f;
}

// Bijective XCD-chunk swizzle (nwg % 8 == 0): physical block b -> work id.
__device__ __forceinline__ int xcd_swizzle(int b, int nwg) {
    return (b & 7) * (nwg >> 3) + (b >> 3);
}

// Wave-local LDS ordering point: compile-time only (DS pipe is in-order per wave).
__device__ __forceinline__ void lds_order() {
    __builtin_amdgcn_sched_barrier(0);
}

// natural-order 8-point DFT: v[k] <- sum_a v[a] W_8^{ak}
__device__ __forceinline__ void dft8(float2 v[8]) {
    const float S = 0.70710678118654752440f;
    float2 a0=caddf(v[0],v[4]), a1=caddf(v[1],v[5]), a2=caddf(v[2],v[6]), a3=caddf(v[3],v[7]);
    float2 b0=csubf(v[0],v[4]);
    float2 t1=csubf(v[1],v[5]);
    float2 t2=csubf(v[2],v[6]);
    float2 t3=csubf(v[3],v[7]);
    float2 b1=make_float2(S*(t1.x+t1.y), S*(t1.y-t1.x));   // *(S,-S) = W8^1
    float2 b2=make_float2(t2.y, -t2.x);                    // *(-i)   = W8^2
    float2 b3=make_float2(S*(t3.y-t3.x), -S*(t3.x+t3.y));  // *(-S,-S)= W8^3
    float2 c0=caddf(a0,a2), c1=caddf(a1,a3), c2=csubf(a0,a2);
    float2 u3=csubf(a1,a3); float2 c3=make_float2(u3.y,-u3.x);
    float2 d0=caddf(b0,b2), d1=caddf(b1,b3), d2=csubf(b0,b2);
    float2 w3=csubf(b1,b3); float2 d3=make_float2(w3.y,-w3.x);
    v[0]=caddf(c0,c1); v[4]=csubf(c0,c1);
    v[2]=caddf(c2,c3); v[6]=csubf(c2,c3);
    v[1]=caddf(d0,d1); v[5]=csubf(d0,d1);
    v[3]=caddf(d2,d3); v[7]=csubf(d2,d3);
}

// v[c] *= w^c, c=1..7. Power tree: short dependency chain, good ILP.
__device__ __forceinline__ void twapply(float2 v[8], float2 w) {
    const float2 w2 = cmulf(w,  w);
    const float2 w3 = cmulf(w2, w);
    const float2 w4 = cmulf(w2, w2);
    const float2 w5 = cmulf(w2, w3);
    const float2 w6 = cmulf(w3, w3);
    const float2 w7 = cmulf(w4, w3);
    v[1] = cmulf(v[1], w);
    v[2] = cmulf(v[2], w2);
    v[3] = cmulf(v[3], w3);
    v[4] = cmulf(v[4], w4);
    v[5] = cmulf(v[5], w5);
    v[6] = cmulf(v[6], w6);
    v[7] = cmulf(v[7], w7);
}

// Per-wave 512-pt FFT. In: v[a] = x[64a + lane]. Out: lane L, reg e = X[(L>>3) + 8*(L&7) + 64e].
// W = this wave's PRIVATE 512-float2 LDS region. No block-wide sync inside.
__device__ __forceinline__ void fft512_reg(float2 v[8], float2* __restrict__ W,
                                           const float2* __restrict__ twg, int lane) {
    dft8(v);
    twapply(v, twg[lane]);                                   // W_512^m, m = lane
    // T1 write: slot(c,m) = 64c + ((m + 2c)&63)  -> rotation: bijective, bank floor
#pragma unroll
    for (int c = 0; c < 8; ++c) W[(c<<6) + ((lane + 2*c)&63)] = v[c];
    lds_order();
    {   // T1 read: lane (c,p) takes m = 8b+p
        const int c = lane>>3, p = lane&7, base = c<<6, off = p + 2*c;
#pragma unroll
        for (int bb = 0; bb < 8; ++bb) v[bb] = W[base + (((bb<<3) + off)&63)];
    }
    lds_order();
    dft8(v);
    twapply(v, twg[(lane&7)<<3]);                            // W_64^p = W_512^{8p}
    {   // T2 write: slot(c,p,d) at 64c + ((8d + (p^d) + 2c)&63)  (XOR: bijective)
        const int c = lane>>3, p = lane&7, base = c<<6, r2 = 2*c;
#pragma unroll
        for (int d = 0; d < 8; ++d) W[base + (((d<<3) + (p^d) + r2)&63)] = v[d];
    }
    lds_order();
    {   // T2 read: lane (c,d) takes p = 0..7
        const int c = lane>>3, d = lane&7, base = c<<6, off = (d<<3) + 2*c;
#pragma unroll
        for (int p = 0; p < 8; ++p) v[p] = W[base + ((off + (p^d))&63)];
    }
    lds_order();
    dft8(v);
}

__global__ void twiddle_kernel(float2* __restrict__ tw) {
    const int k = threadIdx.x;            // 0..255
    const double ang = -2.0 * M_PI * (double)k / 512.0;
    tw[k] = make_float2((float)cos(ang), (float)sin(ang));
}

// Pass 1 (R12): 256 thr = 4 waves = 4 rows. Grid = chunk*128, XCD-swizzled.
// 12 pinned float4 loads -> gray -> LDS redistribute (R10 mapping) -> FFT ->
// streaming scratch write ([img][rg4][col][j4]).
__global__ __launch_bounds__(256, 4)
void row_fft_kernel(const float* __restrict__ gen, const float* __restrict__ tgt,
                    const float2* __restrict__ twg, float2* __restrict__ scratch,
                    int b0, int nwg) {
    __shared__ float2 SBUF[4 * 512];      // 16 KB: per-wave region (pack -> FFT -> staging)
    const int w = xcd_swizzle((int)blockIdx.x, nwg);
    const int tid = threadIdx.x, wave = tid>>6, lane = tid&63;
    const int img = w>>7, rg4 = w&127;
    const int b = b0 + img, r = (rg4<<2) + wave;

    const size_t rowoff = ((size_t)b * 3 * 512 + r) * 512;
    const float4* gR4 = reinterpret_cast<const float4*>(gen + rowoff);   // +65536 f4 per channel
    const float4* tR4 = reinterpret_cast<const float4*>(tgt + rowoff);

    // 12 x float4 loads (1KB per wave-inst), pinned ahead of ALL consumers:
    // sched_barrier(0) forbids sinking any load -> 48 VGPRs of payload stay
    // live -> 12 KB in flight per wave (the R10 intent, now enforced).
    float4 gr0, gg0, gb0, tr0, tg0, tb0, gr1, gg1, gb1, tr1, tg1, tb1;
    {
        const int f0 = lane, f1 = 64 + lane;      // float4 index within row (128 per row)
        gr0 = gR4[f0];           gr1 = gR4[f1];
        gg0 = gR4[f0 + 65536];   gg1 = gR4[f1 + 65536];
        gb0 = gR4[f0 + 131072];  gb1 = gR4[f1 + 131072];
        tr0 = tR4[f0];           tr1 = tR4[f1];
        tg0 = tR4[f0 + 65536];   tg1 = tR4[f1 + 65536];
        tb0 = tR4[f0 + 131072];  tb1 = tR4[f1 + 131072];
    }
    __builtin_amdgcn_sched_barrier(0);    // all 12 loads issued before any use

    float2* W = SBUF + (wave<<9);
    // pack gray pairs into W (R10 mapping, HW-verified): element i at slot
    // 64a + ((i&63) + 2a)&63, a = i>>6. Write side ~4-way aliasing (noise);
    // read side bank-floor.
    {
        const int i0 = lane<<2;           // k=0: elements 4L..4L+3
        const int a  = i0>>6;
        const int base = a<<6, rotm = (i0&63) + (a<<1);
        W[base + ( rotm      & 63)] = make_float2(gray01(gr0.x, gg0.x, gb0.x), gray01(tr0.x, tg0.x, tb0.x));
        W[base + ((rotm + 1) & 63)] = make_float2(gray01(gr0.y, gg0.y, gb0.y), gray01(tr0.y, tg0.y, tb0.y));
        W[base + ((rotm + 2) & 63)] = make_float2(gray01(gr0.z, gg0.z, gb0.z), gray01(tr0.z, tg0.z, tb0.z));
        W[base + ((rotm + 3) & 63)] = make_float2(gray01(gr0.w, gg0.w, gb0.w), gray01(tr0.w, tg0.w, tb0.w));
    }
    {
        const int i0 = 256 + (lane<<2);   // k=1: elements 256+4L..
        const int a  = i0>>6;
        const int base = a<<6, rotm = (i0&63) + (a<<1);
        W[base + ( rotm      & 63)] = make_float2(gray01(gr1.x, gg1.x, gb1.x), gray01(tr1.x, tg1.x, tb1.x));
        W[base + ((rotm + 1) & 63)] = make_float2(gray01(gr1.y, gg1.y, gb1.y), gray01(tr1.y, tg1.y, tb1.y));
        W[base + ((rotm + 2) & 63)] = make_float2(gray01(gr1.z, gg1.z, gb1.z), gray01(tr1.z, tg1.z, tb1.z));
        W[base + ((rotm + 3) & 63)] = make_float2(gray01(gr1.w, gg1.w, gb1.w), gray01(tr1.w, tg1.w, tb1.w));
    }
    lds_order();
    float2 v[8];
#pragma unroll
    for (int a = 0; a < 8; ++a) v[a] = W[(a<<6) + ((lane + (a<<1)) & 63)];   // x[64a+lane]
    lds_order();                          // T1 below overwrites W: same-wave WAR, in-order DS

    fft512_reg(v, W, twg, lane);

    // out-staging (overlays own FFT region; same-wave WAR safe via in-order DS pipe):
    // region = wave (row r), slot = (col + 8*wave)&511, col = 64e + lane
#pragma unroll
    for (int e = 0; e < 8; ++e) {
        const int col = (e<<6) + lane;
        W[(col + (wave<<3)) & 511] = v[e];
    }
    __syncthreads();                       // REAL barrier: gather reads all 4 regions

    // gather + store: scratch[img][rg4][col][j4], flat = obase + col*4 + j4.
    // thread (cg=tid>>2, j4=tid&3): out idx = it*256 + tid -> block writes one
    // contiguous 16KB region; 512B per wave-inst.
    const size_t obase = ((size_t)img << 18) + ((size_t)rg4 << 11);
    const int cg = tid>>2, j4 = tid&3;
    float2* sj = SBUF + (j4<<9);
#pragma unroll
    for (int it = 0; it < 8; ++it) {
        const int col = cg + (it<<6);
        scratch[obase + (it<<8) + tid] = sj[(col + (j4<<3)) & 511];
    }
}

// PSD combine for one element: F1 = Z[ky][kx], F2 = Z[-ky][-kx].
__device__ __forceinline__ void accum_psd(float2 F1, float2 F2, double& sg, double& st) {
    const float ar = 0.5f*(F1.x + F2.x), ai = 0.5f*(F1.y - F2.y);   // gen spectrum
    const float br = 0.5f*(F1.y + F2.y), bi = 0.5f*(F2.x - F1.x);   // tgt spectrum
    const float pg = fmaf(ar, ar, ai*ai) + 1e-10f;
    const float pt = fmaf(br, br, bi*bi) + 1e-10f;
    sg += (double)log10f(pg);
    st += (double)log10f(pt);
}

// Pass 2 (R7 + R11 layout + R12 load pinning): one WAVE per conjugate column
// pair. Block = 256 thr. Grid = chunk*64, XCD-swizzled. NO __syncthreads.
__global__ __launch_bounds__(256, 4)
void col_fft_reduce_kernel(const float2* __restrict__ scratch,
                           const float2* __restrict__ twg,
                           double2* __restrict__ partial, int b0, int nwg) {
    __shared__ float2 SBUF[4 * 512];      // 16 KB: one private 512-float2 region per wave
    const int w = xcd_swizzle((int)blockIdx.x, nwg);
    const int tid = threadIdx.x, wave = tid>>6, lane = tid&63;
    const int gw = (w<<2) + wave;              // global wave (work) id in dispatch
    const int img = gw>>8, t = gw&255;
    const int b = b0 + img;
    const int kxA = t;
    const int kxB = (t == 0) ? 256 : 512 - t;
    const int colA = ((kxA>>6)<<6) + ((kxA&7)<<3) + ((kxA>>3)&7);
    const int colB = ((kxB>>6)<<6) + ((kxB&7)<<3) + ((kxB>>3)&7);
    float2* W = SBUF + (wave<<9);

    // r = 64a + lane -> rg4 = 16a + (lane>>2), j4 = lane&3:
    // idx = img*2^18 + rg4*2048 + col*4 + j4 = base + a*32768
    const size_t lanoff = ((size_t)(lane>>2)<<11) + (lane&3);
    const float2* srcA = scratch + ((size_t)img<<18) + ((size_t)colA<<2) + lanoff;
    const float2* srcB = scratch + ((size_t)img<<18) + ((size_t)colB<<2) + lanoff;
    float2 va[8], vb[8];
#pragma unroll
    for (int a = 0; a < 8; ++a) va[a] = srcA[a<<15];
#pragma unroll
    for (int a = 0; a < 8; ++a) vb[a] = srcB[a<<15];
    __builtin_amdgcn_sched_barrier(0);    // pin all 16 loads; vb stays in
                                          // flight through FFT A (true prefetch)

    fft512_reg(va, W, twg, lane);

    const int cc = lane>>3, dd = lane&7;
    const int kyb = cc + (dd<<3);            // ky = kyb + 64e

    // publish A natural-ky, read reversed into regs (wave-private, in-order DS)
#pragma unroll
    for (int e = 0; e < 8; ++e) W[kyb + (e<<6)] = va[e];
    lds_order();
    float2 aRev[8];
#pragma unroll
    for (int e = 0; e < 8; ++e) aRev[e] = W[(512 - (kyb + (e<<6))) & 511];
    lds_order();                             // keep FFT B's writes after these reads

    fft512_reg(vb, W, twg, lane);

#pragma unroll
    for (int e = 0; e < 8; ++e) W[kyb + (e<<6)] = vb[e];
    lds_order();
    float2 bRev[8];
#pragma unroll
    for (int e = 0; e < 8; ++e) bRev[e] = W[(512 - (kyb + (e<<6))) & 511];
    lds_order();

    // exclusion: column in box-kx  =>  skip e==0 (ky<64) and e==7 (ky>=448)
    const bool kxinA = (t < 64);             // kxA in [0,64)
    const bool kxinB = (t >= 1 && t <= 64);  // kxB = 512-t in [448,512)

    double sg = 0.0, st = 0.0;
    if (t == 0) {   // both columns self-conjugate: partner is own reversed
#pragma unroll
        for (int e = 0; e < 8; ++e) {
            if (!(kxinA && (e == 0 || e == 7))) accum_psd(va[e], aRev[e], sg, st);
            accum_psd(vb[e], bRev[e], sg, st);   // kx=256 never in box
        }
    } else {        // partner of A is B and vice versa
#pragma unroll
        for (int e = 0; e < 8; ++e) {
            if (!(kxinA && (e == 0 || e == 7))) accum_psd(va[e], bRev[e], sg, st);
            if (!(kxinB && (e == 0 || e == 7))) accum_psd(vb[e], aRev[e], sg, st);
        }
    }
#pragma unroll
    for (int off = 32; off; off >>= 1) {
        sg += __shfl_down(sg, off);
        st += __shfl_down(st, off);
    }
    if (lane == 0) partial[((size_t)b<<8) + t] = make_double2(sg, st);
}

// Sum the 256 per-pair partials of each image into accum[128]. Grid = 64 blocks.
__global__ __launch_bounds__(256)
void reduce_partial_kernel(const double2* __restrict__ partial,
                           double* __restrict__ accum) {
    __shared__ double2 red[4];
    const int img = blockIdx.x, tid = threadIdx.x, wave = tid>>6, lane = tid&63;
    const double2 p = partial[((size_t)img<<8) + tid];
    double sg = p.x, st = p.y;
#pragma unroll
    for (int off = 32; off; off >>= 1) {
        sg += __shfl_down(sg, off);
        st += __shfl_down(st, off);
    }
    if (lane == 0) red[wave] = make_double2(sg, st);
    __syncthreads();
    if (tid == 0) {
        double SG = 0.0, ST = 0.0;
#pragma unroll
        for (int w = 0; w < 4; ++w) { SG += red[w].x; ST += red[w].y; }
        accum[img] = SG;
        accum[64 + img] = ST;
    }
}

__global__ void finalize_kernel(const double* __restrict__ accum,
                                float* __restrict__ out) {
    const int lane = threadIdx.x;   // 64
    double d = fabs(accum[lane] - accum[64 + lane]) * (1.0 / 245760.0);
#pragma unroll
    for (int off = 32; off; off >>= 1) d += __shfl_down(d, off);
    if (lane == 0) out[0] = (float)(d * (1.0 / 64.0));   // WEIGHT = 1.0
}

extern "C" void kernel_launch(void* const* d_in, const int* in_sizes, int n_in,
                              void* d_out, int out_size, void* d_ws, size_t ws_size,
                              hipStream_t stream) {
    (void)in_sizes; (void)n_in; (void)out_size;
    const float* gen = (const float*)d_in[0];
    const float* tgt = (const float*)d_in[1];
    float*   out     = (float*)d_out;
    float2*  tw      = (float2*)d_ws;
    double*  accum   = (double*)((char*)d_ws + 2048);
    double2* partial = (double2*)((char*)d_ws + 4096);            // 64*256*16 B = 256 KB
    float2*  scratch = (float2*)((char*)d_ws + 266240);           // 65*4096

    const size_t per_img = (size_t)512 * 512 * sizeof(float2);
    const size_t avail = (ws_size > 266240) ? (ws_size - 266240) : 0;
    int chunk = 64;                      // shrinks to fit ws (observed: 32 -> 64 MiB)
    while (chunk > 1 && (size_t)chunk * per_img > avail) chunk >>= 1;

    twiddle_kernel<<<1, 256, 0, stream>>>(tw);
    for (int b0 = 0; b0 < 64; b0 += chunk) {
        const int nwr = chunk * 128;     // %8==0 for chunk>=1
        const int nwc = chunk * 64;
        row_fft_kernel<<<dim3(nwr), dim3(256), 0, stream>>>(gen, tgt, tw, scratch, b0, nwr);
        col_fft_reduce_kernel<<<dim3(nwc), dim3(256), 0, stream>>>(scratch, tw, partial, b0, nwc);
    }
    reduce_partial_kernel<<<dim3(64), dim3(256), 0, stream>>>(partial, accum);
    finalize_kernel<<<1, 64, 0, stream>>>(accum, out);
}

// Round 15
// 498.817 us; speedup vs baseline: 1.0160x; 1.0016x over previous
//
#include <hip/hip_runtime.h>
#include <math.h>

#ifndef M_PI
#define M_PI 3.14159265358979323846
#endif

// B=64, C=3, H=W=512.
// Loss = mean_b | mean_hf(log10 PSD(gen_b)) - mean_hf(log10 PSD(tgt_b)) |
// hf region: element EXCLUDED iff ky and kx both in [0,64)u[448,512).
// With ky = cc + 8dd + 64e: ky<64 <=> e==0, ky>=448 <=> e==7. count = 245760.
//
// FFT: 512 = 8*8*8 Cooley-Tukey, per-wave, 8 complex regs/lane, wave-private
// LDS transposes, compile-time-only ordering (R6, verified absmax 0.0).
// R7 (verified): col = one wave per conjugate pair, zero barriers, no atomics.
// R8 (REGRESSED): 16-row blocks. R9 (verified): streaming scratch, row 167->147.
// R10/R11/R12 (NEUTRAL): float4 loads / 4-wave blocks / sched_barrier pinning.
//   R12's key diagnostic FAILED: VGPR stayed 32 -> compiler re-serializes
//   loads at a pass sched_barrier doesn't govern. Row pinned at 2.3TB/s with
//   ~1 load in flight/wave (latency-serialized), all pipes <30%.
//
// R13 (resubmitted verbatim -- acquisition timeout, never ran):
//   ASYNC DMA input staging -- no registers to serialize.
//   Row wave issues 12x global_load_lds (size=16: 1KB/instr, vmcnt-counted,
//   zero VGPR payload) staging its 6 channel-rows (12KB) into a wave-private
//   LDS region; ONE s_waitcnt vmcnt(0); gray read from LDS; FFT overlays the
//   staging region (same-wave in-order DS). 48KB/block -> 3 blocks/CU,
//   12 waves/CU, ~144KB DMA in flight per CU >> 22KB Little's-law need.
//   LDS dest follows the m104/m108 rule: uniform base + lane*16, linear.
//   Col kernel untouched (one change per round).
//
// ws layout: [0,2048) tw[256] ; [2048,3072) double accum[128] ;
//            [4096, 4096+262144) double2 partial[64*256] ;
//            [266240, ...) scratch (16 KB-aligned).
// col index encodes kx: col(kx) = 64*(kx>>6) + 8*(kx&7) + ((kx>>3)&7)

__device__ __forceinline__ float2 cmulf(float2 a, float2 b) {
    return make_float2(fmaf(a.x, b.x, -(a.y * b.y)), fmaf(a.x, b.y, a.y * b.x));
}
__device__ __forceinline__ float2 caddf(float2 a, float2 b){ return make_float2(a.x+b.x, a.y+b.y); }
__device__ __forceinline__ float2 csubf(float2 a, float2 b){ return make_float2(a.x-b.x, a.y-b.y); }

__device__ __forceinline__ float gray01(float R, float G, float B) {
    return fmaf(0.299f, R, fmaf(0.587f, G, fmaf(0.114f, B, 1.0f))) * 0.5f;
}

// Bijective XCD-chunk swizzle (nwg % 8 == 0): physical block b -> work id.
__device__ __forceinline__ int xcd_swizzle(int b, int nwg) {
    return (b & 7) * (nwg >> 3) + (b >> 3);
}

// Wave-local LDS ordering point: compile-time only (DS pipe is in-order per wave).
__device__ __forceinline__ void lds_order() {
    __builtin_amdgcn_sched_barrier(0);
}

// Async 16B-per-lane global->LDS DMA. Per-lane global src; LDS dest must be
// base + lane*16 (wave-uniform base, linear) per the gfx950 HW rule.
__device__ __forceinline__ void gload_lds16(const float* g, float* l) {
    __builtin_amdgcn_global_load_lds(
        (const __attribute__((address_space(1))) void*)g,
        (__attribute__((address_space(3))) void*)l, 16, 0, 0);
}

// natural-order 8-point DFT: v[k] <- sum_a v[a] W_8^{ak}
__device__ __forceinline__ void dft8(float2 v[8]) {
    const float S = 0.70710678118654752440f;
    float2 a0=caddf(v[0],v[4]), a1=caddf(v[1],v[5]), a2=caddf(v[2],v[6]), a3=caddf(v[3],v[7]);
    float2 b0=csubf(v[0],v[4]);
    float2 t1=csubf(v[1],v[5]);
    float2 t2=csubf(v[2],v[6]);
    float2 t3=csubf(v[3],v[7]);
    float2 b1=make_float2(S*(t1.x+t1.y), S*(t1.y-t1.x));   // *(S,-S) = W8^1
    float2 b2=make_float2(t2.y, -t2.x);                    // *(-i)   = W8^2
    float2 b3=make_float2(S*(t3.y-t3.x), -S*(t3.x+t3.y));  // *(-S,-S)= W8^3
    float2 c0=caddf(a0,a2), c1=caddf(a1,a3), c2=csubf(a0,a2);
    float2 u3=csubf(a1,a3); float2 c3=make_float2(u3.y,-u3.x);
    float2 d0=caddf(b0,b2), d1=caddf(b1,b3), d2=csubf(b0,b2);
    float2 w3=csubf(b1,b3); float2 d3=make_float2(w3.y,-w3.x);
    v[0]=caddf(c0,c1); v[4]=csubf(c0,c1);
    v[2]=caddf(c2,c3); v[6]=csubf(c2,c3);
    v[1]=caddf(d0,d1); v[5]=csubf(d0,d1);
    v[3]=caddf(d2,d3); v[7]=csubf(d2,d3);
}

// v[c] *= w^c, c=1..7. Power tree: short dependency chain, good ILP.
__device__ __forceinline__ void twapply(float2 v[8], float2 w) {
    const float2 w2 = cmulf(w,  w);
    const float2 w3 = cmulf(w2, w);
    const float2 w4 = cmulf(w2, w2);
    const float2 w5 = cmulf(w2, w3);
    const float2 w6 = cmulf(w3, w3);
    const float2 w7 = cmulf(w4, w3);
    v[1] = cmulf(v[1], w);
    v[2] = cmulf(v[2], w2);
    v[3] = cmulf(v[3], w3);
    v[4] = cmulf(v[4], w4);
    v[5] = cmulf(v[5], w5);
    v[6] = cmulf(v[6], w6);
    v[7] = cmulf(v[7], w7);
}

// Per-wave 512-pt FFT. In: v[a] = x[64a + lane]. Out: lane L, reg e = X[(L>>3) + 8*(L&7) + 64e].
// W = this wave's PRIVATE 512-float2 LDS region. No block-wide sync inside.
__device__ __forceinline__ void fft512_reg(float2 v[8], float2* __restrict__ W,
                                           const float2* __restrict__ twg, int lane) {
    dft8(v);
    twapply(v, twg[lane]);                                   // W_512^m, m = lane
    // T1 write: slot(c,m) = 64c + ((m + 2c)&63)  -> rotation: bijective, bank floor
#pragma unroll
    for (int c = 0; c < 8; ++c) W[(c<<6) + ((lane + 2*c)&63)] = v[c];
    lds_order();
    {   // T1 read: lane (c,p) takes m = 8b+p
        const int c = lane>>3, p = lane&7, base = c<<6, off = p + 2*c;
#pragma unroll
        for (int bb = 0; bb < 8; ++bb) v[bb] = W[base + (((bb<<3) + off)&63)];
    }
    lds_order();
    dft8(v);
    twapply(v, twg[(lane&7)<<3]);                            // W_64^p = W_512^{8p}
    {   // T2 write: slot(c,p,d) at 64c + ((8d + (p^d) + 2c)&63)  (XOR: bijective)
        const int c = lane>>3, p = lane&7, base = c<<6, r2 = 2*c;
#pragma unroll
        for (int d = 0; d < 8; ++d) W[base + (((d<<3) + (p^d) + r2)&63)] = v[d];
    }
    lds_order();
    {   // T2 read: lane (c,d) takes p = 0..7
        const int c = lane>>3, d = lane&7, base = c<<6, off = (d<<3) + 2*c;
#pragma unroll
        for (int p = 0; p < 8; ++p) v[p] = W[base + ((off + (p^d))&63)];
    }
    lds_order();
    dft8(v);
}

__global__ void twiddle_kernel(float2* __restrict__ tw) {
    const int k = threadIdx.x;            // 0..255
    const double ang = -2.0 * M_PI * (double)k / 512.0;
    tw[k] = make_float2((float)cos(ang), (float)sin(ang));
}

// Pass 1 (R13): 256 thr = 4 waves = 4 rows. Grid = chunk*128, XCD-swizzled.
// Async-DMA stage 6 channel-rows to LDS -> gray from LDS -> FFT (overlays
// staging) -> streaming scratch write ([img][rg4][col][j4]).
__global__ __launch_bounds__(256, 3)
void row_fft_kernel(const float* __restrict__ gen, const float* __restrict__ tgt,
                    const float2* __restrict__ twg, float2* __restrict__ scratch,
                    int b0, int nwg) {
    __shared__ __align__(16) float SBUFF[4 * 3072];   // 48 KB: per-wave 3072-float region
    const int w = xcd_swizzle((int)blockIdx.x, nwg);
    const int tid = threadIdx.x, wave = tid>>6, lane = tid&63;
    const int img = w>>7, rg4 = w&127;
    const int b = b0 + img, r = (rg4<<2) + wave;

    const size_t rowoff = ((size_t)b * 3 * 512 + r) * 512;
    const float* gR = gen + rowoff;       // +262144 floats per channel
    const float* tR = tgt + rowoff;

    float* S = SBUFF + wave * 3072;       // this wave's staging region (12 KB)
    // 12 async DMA loads, 1KB each: channel c half h -> S[c*512 + h*256 + lane*4]
    // (lds arg = uniform base + lane*16B, linear: HW rule satisfied)
#pragma unroll
    for (int c = 0; c < 3; ++c) {
        const float* gc = gR + c * 262144;
        const float* tc = tR + c * 262144;
#pragma unroll
        for (int h = 0; h < 2; ++h) {
            const int off = (h<<8) + (lane<<2);
            gload_lds16(gc + off, S + (c<<9) + off);
            gload_lds16(tc + off, S + 1536 + (c<<9) + off);
        }
    }
    asm volatile("s_waitcnt vmcnt(0)" ::: "memory");   // drain DMA
    __builtin_amdgcn_sched_barrier(0);                 // rule #18 pairing

    float2 v[8];
#pragma unroll
    for (int a = 0; a < 8; ++a) {          // stride-1 LDS reads: conflict-free
        const int idx = (a<<6) + lane;
        v[a] = make_float2(gray01(S[idx], S[512+idx], S[1024+idx]),
                           gray01(S[1536+idx], S[2048+idx], S[2560+idx]));
    }
    lds_order();                           // staging reads before FFT overwrite (in-order DS)

    float2* W = (float2*)S;                // FFT overlays first 4 KB of staging region
    fft512_reg(v, W, twg, lane);

    // out-staging (own region; same-wave WAR safe): slot = (col + 8*wave)&511
#pragma unroll
    for (int e = 0; e < 8; ++e) {
        const int col = (e<<6) + lane;
        W[(col + (wave<<3)) & 511] = v[e];
    }
    __syncthreads();                       // REAL barrier: gather reads all 4 regions

    // gather + store: scratch[img][rg4][col][j4], flat = obase + col*4 + j4.
    // thread (cg=tid>>2, j4=tid&3): out idx = it*256 + tid -> contiguous 16KB
    // per block. Region stride now 1536 float2 (3072 floats).
    const size_t obase = ((size_t)img << 18) + ((size_t)rg4 << 11);
    const int cg = tid>>2, j4 = tid&3;
    float2* sj = (float2*)(SBUFF + j4 * 3072);
#pragma unroll
    for (int it = 0; it < 8; ++it) {
        const int col = cg + (it<<6);
        scratch[obase + (it<<8) + tid] = sj[(col + (j4<<3)) & 511];
    }
}

// PSD combine for one element: F1 = Z[ky][kx], F2 = Z[-ky][-kx].
__device__ __forceinline__ void accum_psd(float2 F1, float2 F2, double& sg, double& st) {
    const float ar = 0.5f*(F1.x + F2.x), ai = 0.5f*(F1.y - F2.y);   // gen spectrum
    const float br = 0.5f*(F1.y + F2.y), bi = 0.5f*(F2.x - F1.x);   // tgt spectrum
    const float pg = fmaf(ar, ar, ai*ai) + 1e-10f;
    const float pt = fmaf(br, br, bi*bi) + 1e-10f;
    sg += (double)log10f(pg);
    st += (double)log10f(pt);
}

// Pass 2 (unchanged from R12): one WAVE per conjugate column pair. Block = 256
// thr. Grid = chunk*64, XCD-swizzled. NO __syncthreads.
__global__ __launch_bounds__(256, 4)
void col_fft_reduce_kernel(const float2* __restrict__ scratch,
                           const float2* __restrict__ twg,
                           double2* __restrict__ partial, int b0, int nwg) {
    __shared__ float2 SBUF[4 * 512];      // 16 KB: one private 512-float2 region per wave
    const int w = xcd_swizzle((int)blockIdx.x, nwg);
    const int tid = threadIdx.x, wave = tid>>6, lane = tid&63;
    const int gw = (w<<2) + wave;              // global wave (work) id in dispatch
    const int img = gw>>8, t = gw&255;
    const int b = b0 + img;
    const int kxA = t;
    const int kxB = (t == 0) ? 256 : 512 - t;
    const int colA = ((kxA>>6)<<6) + ((kxA&7)<<3) + ((kxA>>3)&7);
    const int colB = ((kxB>>6)<<6) + ((kxB&7)<<3) + ((kxB>>3)&7);
    float2* W = SBUF + (wave<<9);

    // r = 64a + lane -> rg4 = 16a + (lane>>2), j4 = lane&3:
    // idx = img*2^18 + rg4*2048 + col*4 + j4 = base + a*32768
    const size_t lanoff = ((size_t)(lane>>2)<<11) + (lane&3);
    const float2* srcA = scratch + ((size_t)img<<18) + ((size_t)colA<<2) + lanoff;
    const float2* srcB = scratch + ((size_t)img<<18) + ((size_t)colB<<2) + lanoff;
    float2 va[8], vb[8];
#pragma unroll
    for (int a = 0; a < 8; ++a) va[a] = srcA[a<<15];
#pragma unroll
    for (int a = 0; a < 8; ++a) vb[a] = srcB[a<<15];
    __builtin_amdgcn_sched_barrier(0);

    fft512_reg(va, W, twg, lane);

    const int cc = lane>>3, dd = lane&7;
    const int kyb = cc + (dd<<3);            // ky = kyb + 64e

    // publish A natural-ky, read reversed into regs (wave-private, in-order DS)
#pragma unroll
    for (int e = 0; e < 8; ++e) W[kyb + (e<<6)] = va[e];
    lds_order();
    float2 aRev[8];
#pragma unroll
    for (int e = 0; e < 8; ++e) aRev[e] = W[(512 - (kyb + (e<<6))) & 511];
    lds_order();                             // keep FFT B's writes after these reads

    fft512_reg(vb, W, twg, lane);

#pragma unroll
    for (int e = 0; e < 8; ++e) W[kyb + (e<<6)] = vb[e];
    lds_order();
    float2 bRev[8];
#pragma unroll
    for (int e = 0; e < 8; ++e) bRev[e] = W[(512 - (kyb + (e<<6))) & 511];
    lds_order();

    // exclusion: column in box-kx  =>  skip e==0 (ky<64) and e==7 (ky>=448)
    const bool kxinA = (t < 64);             // kxA in [0,64)
    const bool kxinB = (t >= 1 && t <= 64);  // kxB = 512-t in [448,512)

    double sg = 0.0, st = 0.0;
    if (t == 0) {   // both columns self-conjugate: partner is own reversed
#pragma unroll
        for (int e = 0; e < 8; ++e) {
            if (!(kxinA && (e == 0 || e == 7))) accum_psd(va[e], aRev[e], sg, st);
            accum_psd(vb[e], bRev[e], sg, st);   // kx=256 never in box
        }
    } else {        // partner of A is B and vice versa
#pragma unroll
        for (int e = 0; e < 8; ++e) {
            if (!(kxinA && (e == 0 || e == 7))) accum_psd(va[e], bRev[e], sg, st);
            if (!(kxinB && (e == 0 || e == 7))) accum_psd(vb[e], aRev[e], sg, st);
        }
    }
#pragma unroll
    for (int off = 32; off; off >>= 1) {
        sg += __shfl_down(sg, off);
        st += __shfl_down(st, off);
    }
    if (lane == 0) partial[((size_t)b<<8) + t] = make_double2(sg, st);
}

// Sum the 256 per-pair partials of each image into accum[128]. Grid = 64 blocks.
__global__ __launch_bounds__(256)
void reduce_partial_kernel(const double2* __restrict__ partial,
                           double* __restrict__ accum) {
    __shared__ double2 red[4];
    const int img = blockIdx.x, tid = threadIdx.x, wave = tid>>6, lane = tid&63;
    const double2 p = partial[((size_t)img<<8) + tid];
    double sg = p.x, st = p.y;
#pragma unroll
    for (int off = 32; off; off >>= 1) {
        sg += __shfl_down(sg, off);
        st += __shfl_down(st, off);
    }
    if (lane == 0) red[wave] = make_double2(sg, st);
    __syncthreads();
    if (tid == 0) {
        double SG = 0.0, ST = 0.0;
#pragma unroll
        for (int w = 0; w < 4; ++w) { SG += red[w].x; ST += red[w].y; }
        accum[img] = SG;
        accum[64 + img] = ST;
    }
}

__global__ void finalize_kernel(const double* __restrict__ accum,
                                float* __restrict__ out) {
    const int lane = threadIdx.x;   // 64
    double d = fabs(accum[lane] - accum[64 + lane]) * (1.0 / 245760.0);
#pragma unroll
    for (int off = 32; off; off >>= 1) d += __shfl_down(d, off);
    if (lane == 0) out[0] = (float)(d * (1.0 / 64.0));   // WEIGHT = 1.0
}

extern "C" void kernel_launch(void* const* d_in, const int* in_sizes, int n_in,
                              void* d_out, int out_size, void* d_ws, size_t ws_size,
                              hipStream_t stream) {
    (void)in_sizes; (void)n_in; (void)out_size;
    const float* gen = (const float*)d_in[0];
    const float* tgt = (const float*)d_in[1];
    float*   out     = (float*)d_out;
    float2*  tw      = (float2*)d_ws;
    double*  accum   = (double*)((char*)d_ws + 2048);
    double2* partial = (double2*)((char*)d_ws + 4096);            // 64*256*16 B = 256 KB
    float2*  scratch = (float2*)((char*)d_ws + 266240);           // 65*4096

    const size_t per_img = (size_t)512 * 512 * sizeof(float2);
    const size_t avail = (ws_size > 266240) ? (ws_size - 266240) : 0;
    int chunk = 64;                      // shrinks to fit ws (observed: 32 -> 64 MiB)
    while (chunk > 1 && (size_t)chunk * per_img > avail) chunk >>= 1;

    twiddle_kernel<<<1, 256, 0, stream>>>(tw);
    for (int b0 = 0; b0 < 64; b0 += chunk) {
        const int nwr = chunk * 128;     // %8==0 for chunk>=1
        const int nwc = chunk * 64;
        row_fft_kernel<<<dim3(nwr), dim3(256), 0, stream>>>(gen, tgt, tw, scratch, b0, nwr);
        col_fft_reduce_kernel<<<dim3(nwc), dim3(256), 0, stream>>>(scratch, tw, partial, b0, nwc);
    }
    reduce_partial_kernel<<<dim3(64), dim3(256), 0, stream>>>(partial, accum);
    finalize_kernel<<<1, 64, 0, stream>>>(accum, out);
}